// Round 1
// baseline (557.373 us; speedup 1.0000x reference)
//
#include <hip/hip_runtime.h>
#include <math.h>

#define HH 256
#define WW 256
#define NB 16
#define NC 32
#define RAD 3
#define KWID 7
#define NTAPS 49
#define TILE 64
#define CW 76      // staging row stride; ALSO dilation-row stride now (4*76 % 32 banks = 16 -> no 8-way conflict)
#define CH 76
#define BUFSZ (CH * CW + 8)   // 5784 floats = 23.1 KB (slack for OOB junk-column reads)
#define BIGF 1e30f
#define FLT_MAX_C 3.402823466e+38f

// ---------------- kernel-table generation (49 taps per channel) ----------------
__global__ void kgen_kernel(const float* __restrict__ fd,
                            const float* __restrict__ fe,
                            float* __restrict__ kd,
                            float* __restrict__ ke) {
    const int c = blockIdx.x;
    const int t = threadIdx.x;
    if (t >= NTAPS) return;
    const int dy = t / KWID - RAD;
    const int dx = t % KWID - RAD;
    const double rho = sqrt((double)(dx * dx + dy * dy));
    const double th  = atan2((double)dy, (double)dx);
    const double alpha = 0.65;
    const double p  = 2.0 * alpha / (2.0 * alpha - 1.0);
    const double nu = (2.0 * alpha - 1.0) * pow(2.0 * alpha, -p);
    const double b1 = cos(th), b2 = sin(th), b3 = cos(2.0 * th), b4 = sin(2.0 * th);
    double s, F;
    s = (double)fd[c * 4 + 0] * b1 + (double)fd[c * 4 + 1] * b2
      + (double)fd[c * 4 + 2] * b3 + (double)fd[c * 4 + 3] * b4;
    F = rho * exp(-s);
    kd[c * NTAPS + t] = (float)(nu * pow(F, p));
    s = (double)fe[c * 4 + 0] * b1 + (double)fe[c * 4 + 1] * b2
      + (double)fe[c * 4 + 2] * b3 + (double)fe[c * 4 + 3] * b4;
    F = rho * exp(-s);
    ke[c * NTAPS + t] = (float)(nu * pow(F, p));
}

// -------- fused convection + dilation + erosion, per (batch, channel, 64x64 tile) --------
// Taps are wave-uniform (address depends only on blockIdx.y) -> scalarized to SGPRs, so
// both tap loops are UNIFIED (all 49 taps live at once, zero VGPR cost). Each LDS row is
// read exactly once per stage. Dilation rows are stored at stride CW=76: 4-row group
// stride = 304 floats = 16 mod 32 banks, breaking the previous 8-way read conflict.
__global__ __launch_bounds__(256, 6) void cde_stencil_kernel(
    const float* __restrict__ xin, const float* __restrict__ csh,
    const float* __restrict__ kdil, const float* __restrict__ kero,
    float* __restrict__ uout)
{
    __shared__ float buf[BUFSZ];

    const int tid = threadIdx.x;
    const int tileId = blockIdx.x;
    const int c = blockIdx.y;
    const int b = blockIdx.z;
    const int ty0 = (tileId >> 2) * TILE;
    const int tx0 = (tileId & 3) * TILE;

    const float cx = csh[c * 2 + 0];
    const float cy = csh[c * 2 + 1];
    const float* __restrict__ xb = xin + (((size_t)b * NC + c) << 16);

    // ---- stage 1: convection (constant per-channel shift -> constant weights/offset) ----
    const float mcx = -cx, mcy = -cy;
    const float fx0 = floorf(mcx), fy0 = floorf(mcy);
    const float wxf = mcx - fx0, wyf = mcy - fy0;
    const int IX = (int)fx0, IY = (int)fy0;
    const float w00 = (1.f - wyf) * (1.f - wxf);
    const float w01 = (1.f - wyf) * wxf;
    const float w10 = wyf * (1.f - wxf);
    const float w11 = wyf * wxf;

    {
        int row = tid / CW;
        int col = tid - row * CW;
        for (int idx = tid; idx < CH * CW; idx += 256) {
            const int gy = ty0 - 6 + row;
            const int gx = tx0 - 6 + col;
            float v = -BIGF;  // dilation-stage pad value (pad of -u is +BIG)
            if (gy >= 0 && gy < HH && gx >= 0 && gx < WW) {
                const int y0 = min(max(gy + IY, 0), HH - 1);
                const int y1 = min(y0 + 1, HH - 1);
                const int x0 = min(max(gx + IX, 0), WW - 1);
                const int x1 = min(x0 + 1, WW - 1);
                const float a00 = xb[(y0 << 8) + x0];
                const float a01 = xb[(y0 << 8) + x1];
                const float a10 = xb[(y1 << 8) + x0];
                const float a11 = xb[(y1 << 8) + x1];
                v = w00 * a00 + w01 * a01 + w10 * a10 + w11 * a11;
            }
            buf[idx] = v;
            // incremental idx -> (row,col): 256 = 3*CW + 28
            col += 28; row += 3;
            if (col >= CW) { col -= CW; ++row; }
        }
    }
    __syncthreads();

    // ---- stage 2: dilation  u1 = max_ky,kx (u0 - k_dil)  on 70x70 (+2 junk cols) ----
    float acc2[5][4];
    int dc0 = 0, dr0 = 0;
    const bool act2 = (tid < 252);  // 18 col-groups (4 wide) x 14 row-strips (5 tall)
    {
        const float* __restrict__ kdc = kdil + c * NTAPS;
        float ta[NTAPS];                  // wave-uniform -> SGPRs
        #pragma unroll
        for (int t = 0; t < NTAPS; ++t) ta[t] = kdc[t];

        if (act2) {
            dc0 = (tid % 18) * 4;
            dr0 = (tid / 18) * 5;

            #pragma unroll
            for (int i = 0; i < 5; ++i)
                #pragma unroll
                for (int j = 0; j < 4; ++j) acc2[i][j] = -FLT_MAX_C;

            const int rb = dr0 * CW + dc0;
            #pragma unroll
            for (int rr = 0; rr < 11; ++rr) {   // each input row read exactly once
                const float* rp = &buf[rb + rr * CW];
                const float4 L0 = *reinterpret_cast<const float4*>(rp);
                const float4 L1 = *reinterpret_cast<const float4*>(rp + 4);
                const float2 L2 = *reinterpret_cast<const float2*>(rp + 8);
                const float ld[10] = {L0.x, L0.y, L0.z, L0.w,
                                      L1.x, L1.y, L1.z, L1.w, L2.x, L2.y};
                #pragma unroll
                for (int i = 0; i < 5; ++i) {
                    const int ky = rr - i;
                    if (ky < 0 || ky > 6) continue;
                    const int kb = ky * KWID;
                    #pragma unroll
                    for (int j = 0; j < 4; ++j) {
                        float m = acc2[i][j];
                        m = fmaxf(m, fmaxf(ld[j + 0] - ta[kb + 0], ld[j + 1] - ta[kb + 1]));
                        m = fmaxf(m, fmaxf(ld[j + 2] - ta[kb + 2], ld[j + 3] - ta[kb + 3]));
                        m = fmaxf(m, fmaxf(ld[j + 4] - ta[kb + 4], ld[j + 5] - ta[kb + 5]));
                        m = fmaxf(m, ld[j + 6] - ta[kb + 6]);
                        acc2[i][j] = m;
                    }
                }
            }
        }
    }
    __syncthreads();  // all stage-2 reads of buf complete -> safe to overwrite

    if (act2) {
        #pragma unroll
        for (int i = 0; i < 5; ++i) {
            const int dr = dr0 + i;
            const int gy = ty0 - 3 + dr;
            const bool rOK = (gy >= 0) && (gy < HH);
            const int gxb = tx0 - 3 + dc0;
            float4 st;
            st.x = (rOK && (gxb + 0) >= 0 && (gxb + 0) < WW) ? acc2[i][0] : BIGF;
            st.y = (rOK && (gxb + 1) >= 0 && (gxb + 1) < WW) ? acc2[i][1] : BIGF;
            st.z = (rOK && (gxb + 2) >= 0 && (gxb + 2) < WW) ? acc2[i][2] : BIGF;
            st.w = (rOK && (gxb + 3) >= 0 && (gxb + 3) < WW) ? acc2[i][3] : BIGF;
            *reinterpret_cast<float4*>(&buf[dr * CW + dc0]) = st;
        }
    }
    __syncthreads();

    // ---- stage 3: erosion  out = min_ky,kx (u1 + k_ero)  on the 64x64 tile ----
    {
        const float* __restrict__ kec = kero + c * NTAPS;
        float te[NTAPS];                  // wave-uniform -> SGPRs
        #pragma unroll
        for (int t = 0; t < NTAPS; ++t) te[t] = kec[t];

        const int ec0 = (tid & 15) * 4;   // 16 col-groups (4 wide)
        const int er0 = (tid >> 4) * 4;   // 16 row-strips (4 tall)

        float acc[4][4];
        #pragma unroll
        for (int i = 0; i < 4; ++i)
            #pragma unroll
            for (int j = 0; j < 4; ++j) acc[i][j] = FLT_MAX_C;

        const int rb = er0 * CW + ec0;
        #pragma unroll
        for (int rr = 0; rr < 10; ++rr) {   // each input row read exactly once
            const float* rp = &buf[rb + rr * CW];
            const float4 L0 = *reinterpret_cast<const float4*>(rp);
            const float4 L1 = *reinterpret_cast<const float4*>(rp + 4);
            const float2 L2 = *reinterpret_cast<const float2*>(rp + 8);
            const float ld[10] = {L0.x, L0.y, L0.z, L0.w,
                                  L1.x, L1.y, L1.z, L1.w, L2.x, L2.y};
            #pragma unroll
            for (int i = 0; i < 4; ++i) {
                const int ky = rr - i;
                if (ky < 0 || ky > 6) continue;
                const int kb = ky * KWID;
                #pragma unroll
                for (int j = 0; j < 4; ++j) {
                    float m = acc[i][j];
                    m = fminf(m, fminf(ld[j + 0] + te[kb + 0], ld[j + 1] + te[kb + 1]));
                    m = fminf(m, fminf(ld[j + 2] + te[kb + 2], ld[j + 3] + te[kb + 3]));
                    m = fminf(m, fminf(ld[j + 4] + te[kb + 4], ld[j + 5] + te[kb + 5]));
                    m = fminf(m, ld[j + 6] + te[kb + 6]);
                    acc[i][j] = m;
                }
            }
        }

        float* __restrict__ ob = uout + (((size_t)b * NC + c) << 16);
        #pragma unroll
        for (int i = 0; i < 4; ++i) {
            float4 st;
            st.x = acc[i][0]; st.y = acc[i][1]; st.z = acc[i][2]; st.w = acc[i][3];
            *reinterpret_cast<float4*>(&ob[((ty0 + er0 + i) << 8) + tx0 + ec0]) = st;
        }
    }
}

// ------- in-place channel mix: out[b,:,p] = W^T u[b,:,p] -------
// 2 pixels per thread (float2): halves load/store instruction count, doubles per-thread
// memory-level parallelism (two independent FMA chains per channel load round).
__global__ __launch_bounds__(256) void mix_kernel(float* u, const float* __restrict__ wmat) {
    const int p = blockIdx.x * 256 + threadIdx.x;        // float2 index within image
    const int b = blockIdx.y;
    float2* ub = reinterpret_cast<float2*>(u + ((size_t)b << 21));  // b * 32 * 65536 floats

    float2 acc[NC];
    {
        const float2 v = ub[p];  // channel 0
        #pragma unroll
        for (int o = 0; o < NC; ++o) {
            const float w = wmat[o];
            acc[o].x = v.x * w;
            acc[o].y = v.y * w;
        }
    }
    #pragma unroll
    for (int i = 1; i < NC; ++i) {
        const float2 v = ub[(i << 15) + p];
        #pragma unroll
        for (int o = 0; o < NC; ++o) {
            const float w = wmat[i * NC + o];   // wave-uniform -> s_load
            acc[o].x = fmaf(v.x, w, acc[o].x);
            acc[o].y = fmaf(v.y, w, acc[o].y);
        }
    }
    #pragma unroll
    for (int o = 0; o < NC; ++o) ub[(o << 15) + p] = acc[o];
}

extern "C" void kernel_launch(void* const* d_in, const int* in_sizes, int n_in,
                              void* d_out, int out_size, void* d_ws, size_t ws_size,
                              hipStream_t stream) {
    const float* x  = (const float*)d_in[0];
    const float* c  = (const float*)d_in[1];
    const float* fd = (const float*)d_in[2];
    const float* fe = (const float*)d_in[3];
    const float* w  = (const float*)d_in[4];
    float* out = (float*)d_out;

    float* kd = (float*)d_ws;            // 32*49 floats
    float* ke = kd + NC * NTAPS;         // 32*49 floats

    kgen_kernel<<<dim3(NC), dim3(64), 0, stream>>>(fd, fe, kd, ke);
    cde_stencil_kernel<<<dim3(16, NC, NB), dim3(256), 0, stream>>>(x, c, kd, ke, out);
    mix_kernel<<<dim3((HH * WW / 2) / 256, NB), dim3(256), 0, stream>>>(out, w);
}

// Round 2
// 455.391 us; speedup vs baseline: 1.2239x; 1.2239x over previous
//
#include <hip/hip_runtime.h>
#include <math.h>

#define HH 256
#define WW 256
#define NB 16
#define NC 32
#define RAD 3
#define KWID 7
#define NTAPS 49
#define TILE 64
#define CW 76      // staging row stride; ALSO dilation-row stride (4*76 % 32 banks = 16 -> no 8-way conflict)
#define CH 76
#define BUFSZ (CH * CW + 8)   // 5784 floats = 23.1 KB (slack for OOB junk-column reads)
#define BIGF 1e30f
#define FLT_MAX_C 3.402823466e+38f

// ---------------- kernel-table generation (49 taps per channel) ----------------
__global__ void kgen_kernel(const float* __restrict__ fd,
                            const float* __restrict__ fe,
                            float* __restrict__ kd,
                            float* __restrict__ ke) {
    const int c = blockIdx.x;
    const int t = threadIdx.x;
    if (t >= NTAPS) return;
    const int dy = t / KWID - RAD;
    const int dx = t % KWID - RAD;
    const double rho = sqrt((double)(dx * dx + dy * dy));
    const double th  = atan2((double)dy, (double)dx);
    const double alpha = 0.65;
    const double p  = 2.0 * alpha / (2.0 * alpha - 1.0);
    const double nu = (2.0 * alpha - 1.0) * pow(2.0 * alpha, -p);
    const double b1 = cos(th), b2 = sin(th), b3 = cos(2.0 * th), b4 = sin(2.0 * th);
    double s, F;
    s = (double)fd[c * 4 + 0] * b1 + (double)fd[c * 4 + 1] * b2
      + (double)fd[c * 4 + 2] * b3 + (double)fd[c * 4 + 3] * b4;
    F = rho * exp(-s);
    kd[c * NTAPS + t] = (float)(nu * pow(F, p));
    s = (double)fe[c * 4 + 0] * b1 + (double)fe[c * 4 + 1] * b2
      + (double)fe[c * 4 + 2] * b3 + (double)fe[c * 4 + 3] * b4;
    F = rho * exp(-s);
    ke[c * NTAPS + t] = (float)(nu * pow(F, p));
}

// -------- fused convection + dilation + erosion, per (batch, channel, 64x64 tile) --------
// UNCHANGED from previous round (control). VALU-issue-bound at 87%; next structural change
// planned: packed-fp16 morphology.
__global__ __launch_bounds__(256, 6) void cde_stencil_kernel(
    const float* __restrict__ xin, const float* __restrict__ csh,
    const float* __restrict__ kdil, const float* __restrict__ kero,
    float* __restrict__ uout)
{
    __shared__ float buf[BUFSZ];

    const int tid = threadIdx.x;
    const int tileId = blockIdx.x;
    const int c = blockIdx.y;
    const int b = blockIdx.z;
    const int ty0 = (tileId >> 2) * TILE;
    const int tx0 = (tileId & 3) * TILE;

    const float cx = csh[c * 2 + 0];
    const float cy = csh[c * 2 + 1];
    const float* __restrict__ xb = xin + (((size_t)b * NC + c) << 16);

    // ---- stage 1: convection (constant per-channel shift -> constant weights/offset) ----
    const float mcx = -cx, mcy = -cy;
    const float fx0 = floorf(mcx), fy0 = floorf(mcy);
    const float wxf = mcx - fx0, wyf = mcy - fy0;
    const int IX = (int)fx0, IY = (int)fy0;
    const float w00 = (1.f - wyf) * (1.f - wxf);
    const float w01 = (1.f - wyf) * wxf;
    const float w10 = wyf * (1.f - wxf);
    const float w11 = wyf * wxf;

    {
        int row = tid / CW;
        int col = tid - row * CW;
        for (int idx = tid; idx < CH * CW; idx += 256) {
            const int gy = ty0 - 6 + row;
            const int gx = tx0 - 6 + col;
            float v = -BIGF;  // dilation-stage pad value (pad of -u is +BIG)
            if (gy >= 0 && gy < HH && gx >= 0 && gx < WW) {
                const int y0 = min(max(gy + IY, 0), HH - 1);
                const int y1 = min(y0 + 1, HH - 1);
                const int x0 = min(max(gx + IX, 0), WW - 1);
                const int x1 = min(x0 + 1, WW - 1);
                const float a00 = xb[(y0 << 8) + x0];
                const float a01 = xb[(y0 << 8) + x1];
                const float a10 = xb[(y1 << 8) + x0];
                const float a11 = xb[(y1 << 8) + x1];
                v = w00 * a00 + w01 * a01 + w10 * a10 + w11 * a11;
            }
            buf[idx] = v;
            // incremental idx -> (row,col): 256 = 3*CW + 28
            col += 28; row += 3;
            if (col >= CW) { col -= CW; ++row; }
        }
    }
    __syncthreads();

    // ---- stage 2: dilation  u1 = max_ky,kx (u0 - k_dil)  on 70x70 (+2 junk cols) ----
    float acc2[5][4];
    int dc0 = 0, dr0 = 0;
    const bool act2 = (tid < 252);  // 18 col-groups (4 wide) x 14 row-strips (5 tall)
    {
        const float* __restrict__ kdc = kdil + c * NTAPS;
        float ta[NTAPS];                  // wave-uniform -> SGPRs
        #pragma unroll
        for (int t = 0; t < NTAPS; ++t) ta[t] = kdc[t];

        if (act2) {
            dc0 = (tid % 18) * 4;
            dr0 = (tid / 18) * 5;

            #pragma unroll
            for (int i = 0; i < 5; ++i)
                #pragma unroll
                for (int j = 0; j < 4; ++j) acc2[i][j] = -FLT_MAX_C;

            const int rb = dr0 * CW + dc0;
            #pragma unroll
            for (int rr = 0; rr < 11; ++rr) {   // each input row read exactly once
                const float* rp = &buf[rb + rr * CW];
                const float4 L0 = *reinterpret_cast<const float4*>(rp);
                const float4 L1 = *reinterpret_cast<const float4*>(rp + 4);
                const float2 L2 = *reinterpret_cast<const float2*>(rp + 8);
                const float ld[10] = {L0.x, L0.y, L0.z, L0.w,
                                      L1.x, L1.y, L1.z, L1.w, L2.x, L2.y};
                #pragma unroll
                for (int i = 0; i < 5; ++i) {
                    const int ky = rr - i;
                    if (ky < 0 || ky > 6) continue;
                    const int kb = ky * KWID;
                    #pragma unroll
                    for (int j = 0; j < 4; ++j) {
                        float m = acc2[i][j];
                        m = fmaxf(m, fmaxf(ld[j + 0] - ta[kb + 0], ld[j + 1] - ta[kb + 1]));
                        m = fmaxf(m, fmaxf(ld[j + 2] - ta[kb + 2], ld[j + 3] - ta[kb + 3]));
                        m = fmaxf(m, fmaxf(ld[j + 4] - ta[kb + 4], ld[j + 5] - ta[kb + 5]));
                        m = fmaxf(m, ld[j + 6] - ta[kb + 6]);
                        acc2[i][j] = m;
                    }
                }
            }
        }
    }
    __syncthreads();  // all stage-2 reads of buf complete -> safe to overwrite

    if (act2) {
        #pragma unroll
        for (int i = 0; i < 5; ++i) {
            const int dr = dr0 + i;
            const int gy = ty0 - 3 + dr;
            const bool rOK = (gy >= 0) && (gy < HH);
            const int gxb = tx0 - 3 + dc0;
            float4 st;
            st.x = (rOK && (gxb + 0) >= 0 && (gxb + 0) < WW) ? acc2[i][0] : BIGF;
            st.y = (rOK && (gxb + 1) >= 0 && (gxb + 1) < WW) ? acc2[i][1] : BIGF;
            st.z = (rOK && (gxb + 2) >= 0 && (gxb + 2) < WW) ? acc2[i][2] : BIGF;
            st.w = (rOK && (gxb + 3) >= 0 && (gxb + 3) < WW) ? acc2[i][3] : BIGF;
            *reinterpret_cast<float4*>(&buf[dr * CW + dc0]) = st;
        }
    }
    __syncthreads();

    // ---- stage 3: erosion  out = min_ky,kx (u1 + k_ero)  on the 64x64 tile ----
    {
        const float* __restrict__ kec = kero + c * NTAPS;
        float te[NTAPS];                  // wave-uniform -> SGPRs
        #pragma unroll
        for (int t = 0; t < NTAPS; ++t) te[t] = kec[t];

        const int ec0 = (tid & 15) * 4;   // 16 col-groups (4 wide)
        const int er0 = (tid >> 4) * 4;   // 16 row-strips (4 tall)

        float acc[4][4];
        #pragma unroll
        for (int i = 0; i < 4; ++i)
            #pragma unroll
            for (int j = 0; j < 4; ++j) acc[i][j] = FLT_MAX_C;

        const int rb = er0 * CW + ec0;
        #pragma unroll
        for (int rr = 0; rr < 10; ++rr) {   // each input row read exactly once
            const float* rp = &buf[rb + rr * CW];
            const float4 L0 = *reinterpret_cast<const float4*>(rp);
            const float4 L1 = *reinterpret_cast<const float4*>(rp + 4);
            const float2 L2 = *reinterpret_cast<const float2*>(rp + 8);
            const float ld[10] = {L0.x, L0.y, L0.z, L0.w,
                                  L1.x, L1.y, L1.z, L1.w, L2.x, L2.y};
            #pragma unroll
            for (int i = 0; i < 4; ++i) {
                const int ky = rr - i;
                if (ky < 0 || ky > 6) continue;
                const int kb = ky * KWID;
                #pragma unroll
                for (int j = 0; j < 4; ++j) {
                    float m = acc[i][j];
                    m = fminf(m, fminf(ld[j + 0] + te[kb + 0], ld[j + 1] + te[kb + 1]));
                    m = fminf(m, fminf(ld[j + 2] + te[kb + 2], ld[j + 3] + te[kb + 3]));
                    m = fminf(m, fminf(ld[j + 4] + te[kb + 4], ld[j + 5] + te[kb + 5]));
                    m = fminf(m, ld[j + 6] + te[kb + 6]);
                    acc[i][j] = m;
                }
            }
        }

        float* __restrict__ ob = uout + (((size_t)b * NC + c) << 16);
        #pragma unroll
        for (int i = 0; i < 4; ++i) {
            float4 st;
            st.x = acc[i][0]; st.y = acc[i][1]; st.z = acc[i][2]; st.w = acc[i][3];
            *reinterpret_cast<float4*>(&ob[((ty0 + er0 + i) << 8) + tx0 + ec0]) = st;
        }
    }
}

// ------- in-place channel mix: out[b,:,p] = W^T u[b,:,p] -------
// Block = 128 consecutive pixels x all 32 channels. Cooperative float4 LDS staging
// (16 KB), then wave w computes output channels [8w, 8w+8) for all 128 px with
// wave-uniform s_load'd weights. acc = float2[8] -> ~32 VGPRs, full occupancy.
// Traffic: exactly 128 MB read + 128 MB write (no amplification). In-place safe:
// each block only touches its own pixel strip.
#define PXS 128
__global__ __launch_bounds__(256) void mix_kernel(float* __restrict__ u,
                                                  const float* __restrict__ wmat) {
    __shared__ float s[NC * PXS];   // 16 KB

    const int tid = threadIdx.x;
    const int strip = blockIdx.x;                 // 512 strips per image
    const int b = blockIdx.y;
    float* __restrict__ ub = u + ((size_t)b << 21) + strip * PXS;

    // ---- stage all 32 channels x 128 px: 1024 float4, 4 per thread ----
    #pragma unroll
    for (int k = 0; k < 4; ++k) {
        const int idx = tid + k * 256;            // float4 index
        const int i = idx >> 5;                   // channel (128 px = 32 float4)
        const int q = idx & 31;
        const float4 v = *reinterpret_cast<const float4*>(ub + (i << 16) + (q << 2));
        *reinterpret_cast<float4*>(&s[idx << 2]) = v;
    }
    __syncthreads();

    // ---- compute: wave-uniform output-channel group ----
    const int lane = tid & 63;
    const int wv = __builtin_amdgcn_readfirstlane(tid) >> 6;  // provably uniform wave id
    const int o0 = wv * 8;

    float2 acc[8];
    #pragma unroll
    for (int o = 0; o < 8; ++o) { acc[o].x = 0.f; acc[o].y = 0.f; }

    #pragma unroll
    for (int i = 0; i < NC; ++i) {
        const float2 v = *reinterpret_cast<const float2*>(&s[i * PXS + 2 * lane]);
        const float* __restrict__ wr = wmat + i * NC + o0;    // uniform -> s_load_dwordx8
        #pragma unroll
        for (int o = 0; o < 8; ++o) {
            const float w = wr[o];
            acc[o].x = fmaf(v.x, w, acc[o].x);
            acc[o].y = fmaf(v.y, w, acc[o].y);
        }
    }

    #pragma unroll
    for (int o = 0; o < 8; ++o) {
        *reinterpret_cast<float2*>(ub + ((size_t)(o0 + o) << 16) + 2 * lane) = acc[o];
    }
}

extern "C" void kernel_launch(void* const* d_in, const int* in_sizes, int n_in,
                              void* d_out, int out_size, void* d_ws, size_t ws_size,
                              hipStream_t stream) {
    const float* x  = (const float*)d_in[0];
    const float* c  = (const float*)d_in[1];
    const float* fd = (const float*)d_in[2];
    const float* fe = (const float*)d_in[3];
    const float* w  = (const float*)d_in[4];
    float* out = (float*)d_out;

    float* kd = (float*)d_ws;            // 32*49 floats
    float* ke = kd + NC * NTAPS;         // 32*49 floats

    kgen_kernel<<<dim3(NC), dim3(64), 0, stream>>>(fd, fe, kd, ke);
    cde_stencil_kernel<<<dim3(16, NC, NB), dim3(256), 0, stream>>>(x, c, kd, ke, out);
    mix_kernel<<<dim3((HH * WW) / PXS, NB), dim3(256), 0, stream>>>(out, w);
}